// Round 5
// baseline (3587.897 us; speedup 1.0000x reference)
//
#include <hip/hip_runtime.h>

// Program-guided CNN executor — split-bf16 MFMA, oc+spatial-split persistent.
// B=32, T=30, C=128, 14x14 (P=196). 256 WGs = 32 b x 4 oc-tiles (mt) x 2
// spatial halves (7 rows each). WG = 256 thr (4 waves); wave w computes
// rows {2w, 2w+1} of its half (one 32-pos N-tile). The 8 WGs of one b sync
// between conv stages via monotone atomic barriers (8 arrivals, agent scope).
// Conv = implicit GEMM over 9 taps; fp32 = WhXh + WhXl + WlXh (3x bf16 MFMA).
// Weights register-double-buffered one chunk ahead. Halves of the same (b,mt)
// are 128 apart in blockIdx -> same XCD (%8 heuristic) -> L2 dedups weights.

#define NSTEP 30
#define CD 147456            // 128*128*9
#define P 196
#define FSZ 25088            // 128*196 floats per (b, buffer)
#define LROW 18              // LDS row: 16 packed u32 (hi|lo) + 2 pad
#define LPOS 176             // 144 staged positions + pad rows for OOB tap reads
#define LBUF (LPOS*LROW)

typedef __attribute__((ext_vector_type(8))) short short8;
typedef __attribute__((ext_vector_type(16))) float f32x16;

__constant__ int KIND_TBL[44] = {
  0,0,0,0,1,3,3,3,3,3, 2,2,2,2,2,2,2,2,2,2,
  2,2,2,2,2,2,3,3,3,2, 2,2,2,2,2,2,2,2,2,2, 2,2,3,2};
__constant__ int MIDX_TBL[44] = {
  0,0,0,0,0,0,1,2,3,4, 1,2,3,4,5,6,7,8,9,10,
  11,12,13,14,15,16,5,6,7,17, 18,19,20,21,22,23,24,25,26,27, 28,29,8,30};

__device__ __forceinline__ uint32_t bf16_rne(float x) {
  uint32_t u = __float_as_uint(x);
  return (u + 0x7fffu + ((u >> 16) & 1u)) >> 16;
}
__device__ __forceinline__ uint32_t pack_hl(float x) {
  uint32_t h = bf16_rne(x);
  float rest = x - __uint_as_float(h << 16);
  uint32_t l = bf16_rne(rest);
  return (h << 16) | l;
}
__device__ __forceinline__ float ld_sc0(const float* p) {  // L1-bypass agent load
  return __hip_atomic_load(p, __ATOMIC_RELAXED, __HIP_MEMORY_SCOPE_AGENT);
}

// Per-b barrier among the 8 WGs of one batch element (monotone counter).
__device__ __forceinline__ void bbar(int* __restrict__ ctr, int target) {
  __syncthreads();
  if (threadIdx.x == 0) {
    __hip_atomic_fetch_add(ctr, 1, __ATOMIC_RELEASE, __HIP_MEMORY_SCOPE_AGENT);
    while (__hip_atomic_load(ctr, __ATOMIC_ACQUIRE, __HIP_MEMORY_SCOPE_AGENT) < target)
      __builtin_amdgcn_s_sleep(2);
  }
  __syncthreads();
}

// Coalesced weight repack. One block per 16-ic chunk C (856 total). Two
// passes of 64 ocs: stage contiguous 144-float (16 ic x 9 tap) rows in LDS,
// then emit the packed layout as coalesced dword runs.
// Output per (C,tap) 8KB block: [mt(4)][hl(2)][lane(64)][4 u32],
// lane=(oc%32)|((ic8)<<5), u32 q packs ic pair (q*2, q*2+1).
__global__ void __launch_bounds__(256) repack_kernel(
    const float* __restrict__ sw1, const float* __restrict__ sw2,
    const float* __restrict__ mu, const float* __restrict__ mb,
    uint32_t* __restrict__ Wp)
{
  __shared__ float lds[64 * 144];
  const int C = blockIdx.x;
  const float* src; int nic, lc;
  if (C < 64)       { src = sw1; nic = 1024; lc = C; }
  else if (C < 72)  { src = sw2; nic = 128;  lc = C - 64; }
  else if (C < 568) { int u = (C - 72) >> 4, r = (C - 72) & 15;
                      src = mu + (size_t)u * 2 * CD + (size_t)(r >> 3) * CD;
                      nic = 128; lc = r & 7; }
  else              { int j = (C - 568) >> 5, r = (C - 568) & 31;
                      const float* base = mb + (size_t)j * 4 * CD;
                      if (r < 16)      { src = base;                  nic = 256; lc = r; }
                      else if (r < 24) { src = base + 2 * (size_t)CD; nic = 128; lc = r - 16; }
                      else             { src = base + 3 * (size_t)CD; nic = 128; lc = r - 24; } }
  const int tid = threadIdx.x;
  uint32_t* outc = Wp + (size_t)C * 9 * 2048;
#pragma unroll
  for (int pass = 0; pass < 2; ++pass) {
    const int oc0 = pass * 64;
    for (int k = 0; k < 36; ++k) {               // load 64 x 144 floats, coalesced
      int i = tid + 256 * k;
      int ocl = i / 144, e = i - ocl * 144;
      lds[i] = src[((size_t)(oc0 + ocl) * nic + lc * 16) * 9 + e];
    }
    __syncthreads();
    for (int k = 0; k < 36; ++k) {               // emit 9216 dwords, coalesced
      int o = tid + 256 * k;                     // tap(9) x mtl(2) x hl(2) x lane(64) x q(4)
      int tap = o / 1024, r = o - tap * 1024;
      int mtl = r >> 9, hl = (r >> 8) & 1, lane = (r >> 2) & 63, q = o & 3;
      int ocl = mtl * 32 + (lane & 31);
      int icl = (lane >> 5) * 8 + q * 2;
      float x0 = lds[ocl * 144 + icl * 9 + tap];
      float x1 = lds[ocl * 144 + (icl + 1) * 9 + tap];
      uint32_t h0 = bf16_rne(x0), h1 = bf16_rne(x1);
      uint32_t v;
      if (hl) {
        uint32_t l0 = bf16_rne(x0 - __uint_as_float(h0 << 16));
        uint32_t l1 = bf16_rne(x1 - __uint_as_float(h1 << 16));
        v = l0 | (l1 << 16);
      } else {
        v = h0 | (h1 << 16);
      }
      int mt = pass * 2 + mtl;
      outc[tap * 2048 + mt * 512 + hl * 256 + lane * 4 + q] = v;
    }
    __syncthreads();
  }
}

union BU { uint32_t u[4]; uint4 v; short8 s8; };

__device__ __forceinline__ void load_wchunk(const uint32_t* __restrict__ wb,
                                            BU* wh, BU* wl) {
#pragma unroll
  for (int t = 0; t < 9; ++t) {
    wh[t].v = *(const uint4*)(wb + t * 2048);
    wl[t].v = *(const uint4*)(wb + t * 2048 + 256);
  }
}

__device__ __forceinline__ void mfma_chunk(const uint32_t* __restrict__ sb,
                                           int pwbase, const BU* wh, const BU* wl,
                                           f32x16& acc) {
  const int TAPOFF[9] = {0, 1, 2, 16, 17, 18, 32, 33, 34};
#pragma unroll
  for (int tap = 0; tap < 9; ++tap) {
    const int pw = pwbase + TAPOFF[tap] * LROW;
    uint2 q0 = *(const uint2*)(sb + pw);
    uint2 q1 = *(const uint2*)(sb + pw + 2);
    uint2 q2 = *(const uint2*)(sb + pw + 4);
    uint2 q3 = *(const uint2*)(sb + pw + 6);
    BU Bh, Bl;
    Bh.u[0] = __builtin_amdgcn_perm(q0.y, q0.x, 0x07060302u);
    Bh.u[1] = __builtin_amdgcn_perm(q1.y, q1.x, 0x07060302u);
    Bh.u[2] = __builtin_amdgcn_perm(q2.y, q2.x, 0x07060302u);
    Bh.u[3] = __builtin_amdgcn_perm(q3.y, q3.x, 0x07060302u);
    Bl.u[0] = __builtin_amdgcn_perm(q0.y, q0.x, 0x05040100u);
    Bl.u[1] = __builtin_amdgcn_perm(q1.y, q1.x, 0x05040100u);
    Bl.u[2] = __builtin_amdgcn_perm(q2.y, q2.x, 0x05040100u);
    Bl.u[3] = __builtin_amdgcn_perm(q3.y, q3.x, 0x05040100u);
    acc = __builtin_amdgcn_mfma_f32_32x32x16_bf16(wh[tap].s8, Bh.s8, acc, 0, 0, 0);
    acc = __builtin_amdgcn_mfma_f32_32x32x16_bf16(wh[tap].s8, Bl.s8, acc, 0, 0, 0);
    acc = __builtin_amdgcn_mfma_f32_32x32x16_bf16(wl[tap].s8, Bh.s8, acc, 0, 0, 0);
  }
}

// One conv3x3 (nc*16 input ch) producing this WG's 32-oc slice (mt) over its
// 7-row spatial half. 256 threads; all 4 waves compute and stage.
__device__ __forceinline__ void conv_run(
    uint32_t sbuf[2][LBUF],
    const float* __restrict__ in0, const float* __restrict__ in1, int split, int nc,
    int C0, int mt, int half,
    const uint32_t* __restrict__ Wp, const float* __restrict__ bias,
    float* __restrict__ dst, float* __restrict__ dst2, float* __restrict__ zb,
    const int* imgoff)
{
  const int tid = threadIdx.x;
  const int w = tid >> 6, lane = tid & 63, l31 = lane & 31, kq = lane >> 5;
  const int ic16 = tid >> 4, pl = tid & 15;
  const int pwbase = (32 * w + l31) * LROW + kq * 8;
  const uint32_t* wbase = Wp + (size_t)C0 * 9 * 2048 + mt * 512 + lane * 4;

  f32x16 acc;
#pragma unroll
  for (int i = 0; i < 16; ++i) acc[i] = 0.f;

  BU whA[9], wlA[9], whB[9], wlB[9];
  load_wchunk(wbase, whA, wlA);
  { // stage chunk 0 (144 positions x 16 ch)
    const float* src = in0 + (size_t)ic16 * P;
#pragma unroll
    for (int i = 0; i < 9; ++i) {
      int off = imgoff[i];
      float x = (off >= 0) ? ld_sc0(src + off) : 0.f;
      sbuf[0][(pl + 16 * i) * LROW + ic16] = pack_hl(x);
    }
  }
  __syncthreads();

  int c = 0;
  while (true) {
    { // even chunk: consume A, prefetch into B
      const bool more = c + 1 < nc;
      float sv[9];
      if (more) {
        const int cn = c + 1;
        const float* src = (cn < split) ? in0 + (size_t)(cn * 16 + ic16) * P
                                        : in1 + (size_t)((cn - split) * 16 + ic16) * P;
#pragma unroll
        for (int i = 0; i < 9; ++i) {
          int off = imgoff[i];
          sv[i] = (off >= 0) ? ld_sc0(src + off) : 0.f;
        }
        load_wchunk(wbase + (size_t)(c + 1) * 9 * 2048, whB, wlB);
      }
      mfma_chunk(&sbuf[c & 1][0], pwbase, whA, wlA, acc);
      if (more) {
#pragma unroll
        for (int i = 0; i < 9; ++i)
          sbuf[(c + 1) & 1][(pl + 16 * i) * LROW + ic16] = pack_hl(sv[i]);
      }
      __syncthreads();
      if (++c >= nc) break;
    }
    { // odd chunk: consume B, prefetch into A
      const bool more = c + 1 < nc;
      float sv[9];
      if (more) {
        const int cn = c + 1;
        const float* src = (cn < split) ? in0 + (size_t)(cn * 16 + ic16) * P
                                        : in1 + (size_t)((cn - split) * 16 + ic16) * P;
#pragma unroll
        for (int i = 0; i < 9; ++i) {
          int off = imgoff[i];
          sv[i] = (off >= 0) ? ld_sc0(src + off) : 0.f;
        }
        load_wchunk(wbase + (size_t)(c + 1) * 9 * 2048, whA, wlA);
      }
      mfma_chunk(&sbuf[c & 1][0], pwbase, whB, wlB, acc);
      if (more) {
#pragma unroll
        for (int i = 0; i < 9; ++i)
          sbuf[(c + 1) & 1][(pl + 16 * i) * LROW + ic16] = pack_hl(sv[i]);
      }
      __syncthreads();
      if (++c >= nc) break;
    }
  }

  { // epilogue: bias (+relu), store fp32
    const int ox = l31 & 15, oyl = 2 * w + (l31 >> 4);
    if (ox < 14 && oyl < 7) {
      const int oy = half * 7 + oyl;
#pragma unroll
      for (int reg = 0; reg < 16; ++reg) {
        int row = (reg & 3) + 8 * (reg >> 2) + 4 * kq;
        int oc = mt * 32 + row;
        float v = acc[reg];
        if (bias) v += bias[row];
        v = fmaxf(v, 0.f);
        dst[(size_t)oc * P + oy * 14 + ox] = v;
        if (dst2) dst2[(size_t)oc * P + oy * 14 + ox] = v;
        if (zb)   zb[(size_t)oc * P + oy * 14 + ox] = 0.f;
      }
    }
  }
}

__global__ void __launch_bounds__(256, 2) persist_kernel(
    const float* __restrict__ feats, const int* __restrict__ progs,
    const float* __restrict__ sb1, const float* __restrict__ sb2,
    const uint32_t* __restrict__ Wp,
    float* __restrict__ feat, float* __restrict__ outb, float* __restrict__ saved,
    float* __restrict__ h1, float* __restrict__ h2, int* __restrict__ ctr)
{
  __shared__ uint32_t s_act[2][LBUF];
  const int tid = threadIdx.x;
  const int idx = blockIdx.x;
  const int half = idx >> 7;           // halves 128 apart -> same XCD (%8)
  const int bm = idx & 127;
  const int b = bm >> 2, mt = bm & 3;
  const size_t bo = (size_t)b * FSZ;
  int* myctr = ctr + b * 32;
  int phase = 0;

  // staged position p = pl + 16*i: local row i (0..8), col pl (0..15)
  // global row = half*7 + i - 1, global col = pl - 1
  int imgoff[9];
  {
    const int pl = tid & 15;
    const int gc = pl - 1;
#pragma unroll
    for (int i = 0; i < 9; ++i) {
      int gr = half * 7 + i - 1;
      imgoff[i] = (gr >= 0 && gr < 14 && gc >= 0 && gc < 14) ? gr * 14 + gc : -1;
    }
  }

  conv_run(s_act, feats + (size_t)b * 1024 * P, nullptr, 1 << 28, 64, 0, mt, half, Wp,
           sb1 + mt * 32, h1 + bo, nullptr, nullptr, imgoff);
  bbar(myctr, ++phase * 8);
  conv_run(s_act, h1 + bo, nullptr, 1 << 28, 8, 64, mt, half, Wp,
           sb2 + mt * 32, feat + bo, outb + bo, saved + bo, imgoff);
  bbar(myctr, ++phase * 8);

  for (int s = 0; s < NSTEP; ++s) {
    int tok = progs[b * NSTEP + (NSTEP - 1 - s)];
    int kind = KIND_TBL[tok], mi = MIDX_TBL[tok];
    if (kind == 0) continue;
    if (kind == 1) {                 // scene: saved <- out (own region); out <- unary0(feat)
      for (int i = tid; i < 32 * 98; i += 256) {
        int ch = i / 98, pos = i - ch * 98 + half * 98;
        size_t a = bo + (size_t)(mt * 32 + ch) * P + pos;
        saved[a] = ld_sc0(&outb[a]);
      }
      int C0 = 72 + mi * 16;
      conv_run(s_act, feat + bo, nullptr, 1 << 28, 8, C0, mt, half, Wp, nullptr,
               h1 + bo, nullptr, nullptr, imgoff);
      bbar(myctr, ++phase * 8);
      conv_run(s_act, h1 + bo, nullptr, 1 << 28, 8, C0 + 8, mt, half, Wp, nullptr,
               outb + bo, nullptr, nullptr, imgoff);
      bbar(myctr, ++phase * 8);
    } else if (kind == 2) {          // unary
      int C0 = 72 + mi * 16;
      conv_run(s_act, outb + bo, nullptr, 1 << 28, 8, C0, mt, half, Wp, nullptr,
               h1 + bo, nullptr, nullptr, imgoff);
      bbar(myctr, ++phase * 8);
      conv_run(s_act, h1 + bo, nullptr, 1 << 28, 8, C0 + 8, mt, half, Wp, nullptr,
               outb + bo, nullptr, nullptr, imgoff);
      bbar(myctr, ++phase * 8);
    } else {                         // binary
      int C0 = 568 + mi * 32;
      conv_run(s_act, outb + bo, saved + bo, 8, 16, C0, mt, half, Wp, nullptr,
               h1 + bo, nullptr, nullptr, imgoff);
      bbar(myctr, ++phase * 8);
      conv_run(s_act, h1 + bo, nullptr, 1 << 28, 8, C0 + 16, mt, half, Wp, nullptr,
               h2 + bo, nullptr, nullptr, imgoff);
      bbar(myctr, ++phase * 8);
      conv_run(s_act, h2 + bo, nullptr, 1 << 28, 8, C0 + 24, mt, half, Wp, nullptr,
               outb + bo, nullptr, nullptr, imgoff);
      bbar(myctr, ++phase * 8);
    }
  }
}

// ---- tail ----
__global__ void __launch_bounds__(256) cls_pool_kernel(
    const float* __restrict__ x, const float* __restrict__ Wc,
    const float* __restrict__ bc, float* __restrict__ hB)
{
  const int b = blockIdx.y, og = blockIdx.x;
  const int oc0 = og * 64;
  __shared__ float s[16 * P];
  const float* xb = x + (size_t)b * FSZ;
  const int tid = threadIdx.x;
  float acc[13][4];
#pragma unroll
  for (int k = 0; k < 13; ++k) { acc[k][0] = acc[k][1] = acc[k][2] = acc[k][3] = 0.f; }
  for (int c0 = 0; c0 < 128; c0 += 16) {
    __syncthreads();
    for (int i = tid; i < 16 * P; i += 256) s[i] = xb[(size_t)c0 * P + i];
    __syncthreads();
#pragma unroll
    for (int k = 0; k < 13; ++k) {
      const int idx = k * 256 + tid;
      if (idx < 64 * 49) {
        const int oc = oc0 + idx / 49, pp = idx % 49;
        const int py = pp / 7, px = pp % 7;
        const int b0 = 2 * py * 14 + 2 * px, b1 = b0 + 14;
        const float* wr = Wc + (size_t)oc * 128 + c0;
#pragma unroll
        for (int ic = 0; ic < 16; ++ic) {
          const float w = wr[ic];
          const float* sp = s + ic * P;
          const float2 r0 = *(const float2*)(sp + b0);
          const float2 r1 = *(const float2*)(sp + b1);
          acc[k][0] = fmaf(w, r0.x, acc[k][0]);
          acc[k][1] = fmaf(w, r0.y, acc[k][1]);
          acc[k][2] = fmaf(w, r1.x, acc[k][2]);
          acc[k][3] = fmaf(w, r1.y, acc[k][3]);
        }
      }
    }
  }
#pragma unroll
  for (int k = 0; k < 13; ++k) {
    const int idx = k * 256 + tid;
    if (idx < 64 * 49) {
      const int oc = oc0 + idx / 49, pp = idx % 49;
      const float m = fmaxf(fmaxf(acc[k][0], acc[k][1]), fmaxf(acc[k][2], acc[k][3]));
      hB[(size_t)b * 25088 + (size_t)oc * 49 + pp] = fmaxf(m + bc[oc], 0.f);
    }
  }
}

__global__ void __launch_bounds__(256) transpose_kernel(
    const float* __restrict__ hB, float* __restrict__ hT)
{
  __shared__ float t[256 * 33];
  const int k0 = blockIdx.x * 256;
  const int tid = threadIdx.x;
  for (int b = 0; b < 32; ++b)
    t[tid * 33 + b] = hB[(size_t)b * 25088 + k0 + tid];
  __syncthreads();
  for (int i = tid; i < 256 * 32; i += 256) {
    const int k = i >> 5, b = i & 31;
    hT[(size_t)(k0 + k) * 32 + b] = t[k * 33 + b];
  }
}

// 256 WGs: 4 oc each, 2-way K split, LDS pair-reduce.
__global__ void __launch_bounds__(256) fc1_kernel(
    const float* __restrict__ hT, const float* __restrict__ W,
    const float* __restrict__ bias, float* __restrict__ o)
{
  const int b = threadIdx.x & 31, j = threadIdx.x >> 5;   // j 0..7
  const int oc = blockIdx.x * 4 + (j & 3);
  const int kh = j >> 2;
  const float* wr = W + (size_t)oc * 25088 + (size_t)kh * 12544;
  const float* ht = hT + (size_t)kh * 12544 * 32;
  float acc = 0.f;
  for (int k = 0; k < 12544; k += 4) {
    const float4 w4 = *(const float4*)(wr + k);
    acc = fmaf(ht[(size_t)(k + 0) * 32 + b], w4.x, acc);
    acc = fmaf(ht[(size_t)(k + 1) * 32 + b], w4.y, acc);
    acc = fmaf(ht[(size_t)(k + 2) * 32 + b], w4.z, acc);
    acc = fmaf(ht[(size_t)(k + 3) * 32 + b], w4.w, acc);
  }
  __shared__ float red[8][32];
  red[j][b] = acc;
  __syncthreads();
  if (j < 4)
    o[(size_t)b * 1024 + oc] = fmaxf(red[j][b] + red[j + 4][b] + bias[oc], 0.f);
}

__global__ void __launch_bounds__(256) fc2_kernel(
    const float* __restrict__ h, const float* __restrict__ W,
    const float* __restrict__ bias, float* __restrict__ out)
{
  const int i = blockIdx.x * 256 + threadIdx.x;
  const int b = i >> 5, oo = i & 31;
  const float* wr = W + (size_t)oo * 1024;
  const float* hr = h + (size_t)b * 1024;
  float acc = bias[oo];
  for (int k = 0; k < 1024; k += 4) {
    const float4 w4 = *(const float4*)(wr + k);
    const float4 h4 = *(const float4*)(hr + k);
    acc = fmaf(h4.x, w4.x, acc);
    acc = fmaf(h4.y, w4.y, acc);
    acc = fmaf(h4.z, w4.z, acc);
    acc = fmaf(h4.w, w4.w, acc);
  }
  out[i] = acc;
}

extern "C" void kernel_launch(void* const* d_in, const int* in_sizes, int n_in,
                              void* d_out, int out_size, void* d_ws, size_t ws_size,
                              hipStream_t stream) {
  const float* feats   = (const float*)d_in[0];
  const int*   progs   = (const int*)  d_in[1];
  const float* stem_w1 = (const float*)d_in[2];
  const float* stem_b1 = (const float*)d_in[3];
  const float* stem_w2 = (const float*)d_in[4];
  const float* stem_b2 = (const float*)d_in[5];
  const float* mem_u   = (const float*)d_in[6];
  const float* mem_b   = (const float*)d_in[7];
  const float* cls_w   = (const float*)d_in[8];
  const float* cls_b   = (const float*)d_in[9];
  const float* fc1_w   = (const float*)d_in[10];
  const float* fc1_b   = (const float*)d_in[11];
  const float* fc2_w   = (const float*)d_in[12];
  const float* fc2_b   = (const float*)d_in[13];

  float* ws = (float*)d_ws;
  const size_t F = (size_t)32 * FSZ;
  float*    feat  = ws;
  float*    outb  = ws + 1 * F;
  float*    saved = ws + 2 * F;
  float*    h1    = ws + 3 * F;
  float*    h2    = ws + 4 * F;
  uint32_t* Wp    = (uint32_t*)(ws + 5 * F);          // 856 x 9 x 8KB = 63.1 MB
  int*      ctr   = (int*)(Wp + (size_t)856 * 9 * 2048);

  hipMemsetAsync(ctr, 0, 32 * 32 * sizeof(int), stream);

  repack_kernel<<<dim3(856), dim3(256), 0, stream>>>(stem_w1, stem_w2, mem_u, mem_b, Wp);

  persist_kernel<<<dim3(256), dim3(256), 0, stream>>>(
      feats, progs, stem_b1, stem_b2, Wp, feat, outb, saved, h1, h2, ctr);

  float* hB   = h1;
  float* hT   = h2;
  float* fc1o = saved;
  cls_pool_kernel<<<dim3(8, 32), dim3(256), 0, stream>>>(outb, cls_w, cls_b, hB);
  transpose_kernel<<<dim3(98), dim3(256), 0, stream>>>(hB, hT);
  fc1_kernel<<<dim3(256), dim3(256), 0, stream>>>(hT, fc1_w, fc1_b, fc1o);
  fc2_kernel<<<dim3(4), dim3(256), 0, stream>>>(fc1o, fc2_w, fc2_b, (float*)d_out);
}